// Round 11
// baseline (16.746 us; speedup 1.0000x reference)
//
#include <hip/hip_runtime.h>
#include <math.h>

#define NB   2
#define NSEQ 1024
#define DD   256
#define LUTN 2048   // intervals; LUTN+1 entries over corr in [-1,1]

#define BM 64
#define BN 64
#define MAGIC 0x5CA1AB1Eu

typedef _Float16 f16;
typedef _Float16 f16x8 __attribute__((ext_vector_type(8)));
typedef float f32x4 __attribute__((ext_vector_type(4)));

__device__ __forceinline__ float wrsum(float v) {
#pragma unroll
  for (int off = 32; off > 0; off >>= 1) v += __shfl_xor(v, off, 64);
  return v;
}

// Single fused kernel, 2 independent blocks/CU (grid 512, 256 threads, 73KB LDS).
// 64x64 tile, 4 waves as 2x2 of 32x32, BK=64 (two 32-f16 chunks), 4 K-steps,
// no-drain s_barriers, depth-1 register prefetch (co-resident block covers
// latency), f16 hi/lo split in-register, stats folded during staging,
// fence-free LUT broadcast with mid-loop spin+stage.
__global__ __launch_bounds__(256, 2) void fused_kernel(
    const float* __restrict__ fg, const float* __restrict__ sg,
    const float* __restrict__ w1, const float* __restrict__ b1,
    const float* __restrict__ w2, const float* __restrict__ b2,
    float* __restrict__ lut, unsigned* __restrict__ flags,
    float* __restrict__ out) {
  __shared__ __align__(16) f16 As[2][2][BM * 64];  // [buf][chunk][row*64 + slot*8], slot ^= row&7
  __shared__ __align__(16) f16 Bs[2][2][BN * 64];
  __shared__ float lut_s[LUTN + 1];
  __shared__ float mA[BM], rA[BM], mB[BN], rB[BN];

  const int t = threadIdx.x;
  const int lane = t & 63;
  const int w = t >> 6;                 // 0..3
  const int wr = w >> 1, wc = w & 1;    // wave tile 32x32 at (wr*32, wc*32)
  const int la = lane & 15;
  const int kg = lane >> 4;             // k-slot group 0..3

  const int bid = blockIdx.x;
  const int x = bid & 7, k = bid >> 3;  // XCD decode: 64 blocks per XCD
  const int panel = x + 8 * (k >> 4);   // 0..31
  const int bz  = panel >> 4;
  const int bm0 = (panel & 15) * BM;
  const int bn0 = (k & 15) * BN;

  const float* fb = fg + ((size_t)bz * NSEQ + bm0) * DD;
  const float* sb = sg + ((size_t)bz * NSEQ + bn0) * DD;

  // staging: row t>>2 (0..63), octet t&3, two 32-float chunks, for both A and B
  const int sr = t >> 2, so = t & 3;

  float4 Ar[4], Br[4];                  // depth-1 prefetch set
  float sAa = 0.f, qAa = 0.f, sBa = 0.f, qBa = 0.f;

  auto ld = [&](int st) {
    const float* p = &fb[(size_t)sr * DD + st * 64 + so * 8];
    Ar[0] = *reinterpret_cast<const float4*>(p);
    Ar[1] = *reinterpret_cast<const float4*>(p + 4);
    Ar[2] = *reinterpret_cast<const float4*>(p + 32);
    Ar[3] = *reinterpret_cast<const float4*>(p + 36);
    const float* q = &sb[(size_t)sr * DD + st * 64 + so * 8];
    Br[0] = *reinterpret_cast<const float4*>(q);
    Br[1] = *reinterpret_cast<const float4*>(q + 4);
    Br[2] = *reinterpret_cast<const float4*>(q + 32);
    Br[3] = *reinterpret_cast<const float4*>(q + 36);
  };

  auto split8 = [](const float4& u0, const float4& u1, f16x8& hv, f16x8& lv,
                   float& sm, float& sq) {
    const float vals[8] = {u0.x, u0.y, u0.z, u0.w, u1.x, u1.y, u1.z, u1.w};
#pragma unroll
    for (int e = 0; e < 8; ++e) {
      sm += vals[e];
      sq = fmaf(vals[e], vals[e], sq);
      const f16 h = (f16)vals[e];
      hv[e] = h;
      lv[e] = (f16)(vals[e] - (float)h);
    }
  };

  auto cvt_write = [&](int pbuf) {
#pragma unroll
    for (int ch = 0; ch < 2; ++ch) {
      f16x8 hv, lv;
      split8(Ar[2 * ch], Ar[2 * ch + 1], hv, lv, sAa, qAa);
      f16* base = &As[pbuf][ch][sr * 64];
      *reinterpret_cast<f16x8*>(&base[(so ^ (sr & 7)) << 3]) = hv;
      *reinterpret_cast<f16x8*>(&base[((4 + so) ^ (sr & 7)) << 3]) = lv;
    }
#pragma unroll
    for (int ch = 0; ch < 2; ++ch) {
      f16x8 hv, lv;
      split8(Br[2 * ch], Br[2 * ch + 1], hv, lv, sBa, qBa);
      f16* base = &Bs[pbuf][ch][sr * 64];
      *reinterpret_cast<f16x8*>(&base[(so ^ (sr & 7)) << 3]) = hv;
      *reinterpret_cast<f16x8*>(&base[((4 + so) ^ (sr & 7)) << 3]) = lv;
    }
  };

  f32x4 acc[2][2] = {};

  auto do_mfma = [&](int p) {
#pragma unroll
    for (int ks = 0; ks < 2; ++ks) {
      f16x8 ah[2], al[2], bh[2], bl[2];
#pragma unroll
      for (int i = 0; i < 2; ++i) {
        const int r = wr * 32 + 16 * i + la;
        const f16* base = &As[p][ks][r * 64];
        ah[i] = *reinterpret_cast<const f16x8*>(&base[(kg ^ (r & 7)) << 3]);
        al[i] = *reinterpret_cast<const f16x8*>(&base[((4 + kg) ^ (r & 7)) << 3]);
      }
#pragma unroll
      for (int j = 0; j < 2; ++j) {
        const int r = wc * 32 + 16 * j + la;
        const f16* base = &Bs[p][ks][r * 64];
        bh[j] = *reinterpret_cast<const f16x8*>(&base[(kg ^ (r & 7)) << 3]);
        bl[j] = *reinterpret_cast<const f16x8*>(&base[((4 + kg) ^ (r & 7)) << 3]);
      }
#pragma unroll
      for (int i = 0; i < 2; ++i)
#pragma unroll
        for (int j = 0; j < 2; ++j) {
          acc[i][j] = __builtin_amdgcn_mfma_f32_16x16x32_f16(ah[i], bh[j], acc[i][j], 0, 0, 0);
          acc[i][j] = __builtin_amdgcn_mfma_f32_16x16x32_f16(ah[i], bl[j], acc[i][j], 0, 0, 0);
          acc[i][j] = __builtin_amdgcn_mfma_f32_16x16x32_f16(al[i], bh[j], acc[i][j], 0, 0, 0);
        }
    }
  };

  ld(0);   // tile 0 in flight under the LUT VALU work

  // ---- LUT slice (4 entries/block via 4 waves), fence-free broadcast. ----
  {
    const float w1a = w1[lane], b1a = b1[lane], w2a = w2[lane];
    const float w1b = w1[lane + 64], b1b = b1[lane + 64], w2b = w2[lane + 64];
    const float b2v = b2[0];
    int e = bid * 4 + w;
#pragma unroll
    for (int pass = 0; pass < 2; ++pass) {
      if (pass == 1) { if (bid == 0 && w == 0) e = LUTN; else break; }
      const float corr = -1.0f + (float)e * (2.0f / LUTN);
      const float a = expf(corr);
      const float x0 = fmaf(a, w1a, b1a);
      const float x1 = fmaf(a, w1b, b1b);
      const float g0 = 0.5f * x0 * (1.0f + erff(x0 * 0.70710678118654752f));
      const float g1 = 0.5f * x1 * (1.0f + erff(x1 * 0.70710678118654752f));
      float acc2 = fmaf(g1, w2b, g0 * w2a);
      acc2 = wrsum(acc2);
      if (lane == 0)
        __hip_atomic_store(&lut[e], acc2 + b2v, __ATOMIC_RELAXED, __HIP_MEMORY_SCOPE_AGENT);
    }
  }

  cvt_write(0);                                      // tile 0 -> buf 0
  asm volatile("s_waitcnt vmcnt(0)" ::: "memory");   // lut stores complete
  __syncthreads();                                   // buf0 ready, all waves drained
  if (t == 0)
    __hip_atomic_store(&flags[bid], MAGIC, __ATOMIC_RELAXED, __HIP_MEMORY_SCOPE_AGENT);

  ld(1);

  // ---- 4-step K-loop (BK=64), no-drain barriers, depth-1 prefetch. ----
  // step 0
  do_mfma(0);
  cvt_write(1);        // tile 1 -> buf 1 (waits its own vmcnt only)
  ld(2);
  asm volatile("s_waitcnt lgkmcnt(0)" ::: "memory");
  __builtin_amdgcn_s_barrier();
  // step 1
  do_mfma(1);
  cvt_write(0);        // tile 2 -> buf 0
  ld(3);
  asm volatile("s_waitcnt lgkmcnt(0)" ::: "memory");
  __builtin_amdgcn_s_barrier();
  // step 2 (+ mid-loop LUT spin & stage: no prefetches left outstanding)
  do_mfma(0);
  cvt_write(1);        // tile 3 -> buf 1
  if (t < 256) {
    while (__hip_atomic_load(&flags[t], __ATOMIC_RELAXED, __HIP_MEMORY_SCOPE_AGENT) != MAGIC) {}
    while (__hip_atomic_load(&flags[t + 256], __ATOMIC_RELAXED, __HIP_MEMORY_SCOPE_AGENT) != MAGIC) {}
  }
#pragma unroll
  for (int i = t; i <= LUTN; i += 256)
    lut_s[i] = __hip_atomic_load(&lut[i], __ATOMIC_RELAXED, __HIP_MEMORY_SCOPE_AGENT);
  asm volatile("s_waitcnt lgkmcnt(0)" ::: "memory");
  __builtin_amdgcn_s_barrier();
  // step 3
  do_mfma(1);

  // ---- Fold stats (4 octet-threads per row) and publish to LDS. ----
  auto red4 = [](float v) {
    v += __shfl_xor(v, 1, 64);
    v += __shfl_xor(v, 2, 64);
    return v;
  };
  sAa = red4(sAa); qAa = red4(qAa);
  sBa = red4(sBa); qBa = red4(qBa);
  if ((t & 3) == 0) {
    const float ma = sAa * (1.0f / DD);
    mA[sr] = ma;
    rA[sr] = 1.0f / fmaxf(sqrtf(fmaxf(qAa - (float)DD * ma * ma, 0.0f)), 1e-6f);
    const float mb_ = sBa * (1.0f / DD);
    mB[sr] = mb_;
    rB[sr] = 1.0f / fmaxf(sqrtf(fmaxf(qBa - (float)DD * mb_ * mb_, 0.0f)), 1e-6f);
  }
  __syncthreads();   // stats + lut_s visible to all

  // ---- Epilogue: rank-1 centering correction -> corr -> LUT -> store. ----
  float msv[2], rsv[2];
#pragma unroll
  for (int j = 0; j < 2; ++j) {
    const int cl = wc * 32 + 16 * j + la;
    msv[j] = mB[cl];
    rsv[j] = rB[cl];
  }
#pragma unroll
  for (int i = 0; i < 2; ++i) {
#pragma unroll
    for (int rg = 0; rg < 4; ++rg) {
      const int rowl = wr * 32 + 16 * i + 4 * kg + rg;
      const float mfv = mA[rowl];
      const float rfv = rA[rowl];
#pragma unroll
      for (int j = 0; j < 2; ++j) {
        // cov_centered/16 = rawdot/16 - 16*mf*ms   (256/16 = 16)
        const float cov = acc[i][j][rg] * (1.0f / 16.0f) - 16.0f * mfv * msv[j];
        float corr = fminf(fmaxf(cov * rfv * rsv[j], -1.0f), 1.0f);
        const float tf = (corr + 1.0f) * (float)(LUTN / 2);
        int idx = (int)tf;
        idx = idx > (LUTN - 1) ? (LUTN - 1) : idx;
        const float fr = tf - (float)idx;
        const float lo = lut_s[idx], hi = lut_s[idx + 1];
        out[((size_t)bz * NSEQ + bm0 + rowl) * NSEQ + bn0 + wc * 32 + 16 * j + la]
            = fmaf(fr, hi - lo, lo);
      }
    }
  }
}

extern "C" void kernel_launch(void* const* d_in, const int* in_sizes, int n_in,
                              void* d_out, int out_size, void* d_ws, size_t ws_size,
                              hipStream_t stream) {
  const float* f  = (const float*)d_in[0];
  const float* s  = (const float*)d_in[1];
  const float* w1 = (const float*)d_in[2];
  const float* b1 = (const float*)d_in[3];
  const float* w2 = (const float*)d_in[4];
  const float* b2 = (const float*)d_in[5];
  float* out = (float*)d_out;

  char* ws = (char*)d_ws;
  float* lut = (float*)(ws);                 // LUTN+1 floats
  unsigned* flags = (unsigned*)(ws + 16384); // 512 flags

  fused_kernel<<<512, 256, 0, stream>>>(f, s, w1, b1, w2, b2, lut, flags, out);
}